// Round 7
// baseline (118.723 us; speedup 1.0000x reference)
//
#include <hip/hip_runtime.h>
#include <math.h>

#define DIM      4096
#define KSEL     2048
#define NTHREADS 256
#define VPT      16            // per row: DIM / NTHREADS
#define NREP     8             // pass-0 histogram replicas
#define HSTRIDE  257           // 257 % 32 == 1 -> replicas on distinct banks
#define HREP_SZ  (NREP * HSTRIDE)

// ---- bit-exact XLA-CPU silu: s = 1/(1+cephes_exp_fma(-x)); h = x*s ----
// Verified absmax == 0.0 in round 4. DO NOT MODIFY.
__device__ __forceinline__ float cephes_expf_fma(float x) {
    const float LOG2EF = 1.44269504088896341f;
    const float C1     = 0.693359375f;
    const float C2     = -2.12194440e-4f;
    float z0 = __builtin_fmaf(x, LOG2EF, 0.5f);
    float fx = floorf(z0);
    float r  = __fsub_rn(x, __fmul_rn(fx, C1));
    r = __builtin_fmaf(fx, -C2, r);
    float zz = __fmul_rn(r, r);
    float y  = 1.9875691500e-4f;
    y = __builtin_fmaf(y, r, 1.3981999507e-3f);
    y = __builtin_fmaf(y, r, 8.3334519073e-3f);
    y = __builtin_fmaf(y, r, 4.1665795894e-2f);
    y = __builtin_fmaf(y, r, 1.6666665459e-1f);
    y = __builtin_fmaf(y, r, 5.0000001201e-1f);
    y = __builtin_fmaf(y, zz, r);
    y = __fadd_rn(y, 1.0f);
    int n = (int)fx;
    float scale = __int_as_float((n + 127) << 23);
    return __fmul_rn(y, scale);
}

__device__ __forceinline__ float silu_ref(float x) {
    float e = cephes_expf_fma(-x);
    float s = __fdiv_rn(1.0f, __fadd_rn(1.0f, e));
    return __fmul_rn(x, s);
}

__global__ __launch_bounds__(NTHREADS) void topk_silu_kernel(
    const float* __restrict__ x, float* __restrict__ out)
{
    const int tid  = threadIdx.x;
    const int lane = tid & 63;
    const int wave = tid >> 6;
    const int rep  = tid & (NREP - 1);

    const size_t rowA = (size_t)blockIdx.x * 2;
    const float4* __restrict__ xa = reinterpret_cast<const float4*>(x + rowA * DIM);
    const float4* __restrict__ xb = reinterpret_cast<const float4*>(x + (rowA + 1) * DIM);
    float4* __restrict__ oa = reinterpret_cast<float4*>(out + rowA * DIM);
    float4* __restrict__ ob = reinterpret_cast<float4*>(out + (rowA + 1) * DIM);

    __shared__ int      hrep[2][HREP_SZ];   // pass-0 replicated histograms
    __shared__ int      hist1[2][256];      // passes 1-3 single histograms
    __shared__ int      wtot[2][4];
    __shared__ unsigned s_dig[2];
    __shared__ int      s_krem[2];

    // ---- load + bit-exact f32 silu; store h bit patterns only ----
    unsigned hbA[VPT], hbB[VPT];
    #pragma unroll
    for (int j = 0; j < 4; ++j) {
        float4 va = xa[j * NTHREADS + tid];
        float4 vb = xb[j * NTHREADS + tid];
        const float* ap = &va.x;
        const float* bp = &vb.x;
        #pragma unroll
        for (int c4 = 0; c4 < 4; ++c4) {
            hbA[j*4+c4] = __float_as_uint(silu_ref(ap[c4]));
            hbB[j*4+c4] = __float_as_uint(silu_ref(bp[c4]));
        }
    }

    // zero histograms (overlaps load/silu latency)
    #pragma unroll
    for (int i = 0; i < (2 * HREP_SZ + NTHREADS - 1) / NTHREADS; ++i) {
        int idx = tid + i * NTHREADS;
        if (idx < 2 * HREP_SZ) (&hrep[0][0])[idx] = 0;
    }
    hist1[0][tid] = 0;
    hist1[1][tid] = 0;
    __syncthreads();

    // ---- pass 0: replicated histogram on top byte of |h| bits ----
    #pragma unroll
    for (int r = 0; r < VPT; ++r) {
        atomicAdd(&hrep[0][rep * HSTRIDE + ((hbA[r] & 0x7FFFFFFFu) >> 24)], 1);
        atomicAdd(&hrep[1][rep * HSTRIDE + ((hbB[r] & 0x7FFFFFFFu) >> 24)], 1);
    }
    __syncthreads();

    int cA = 0, cB = 0;
    #pragma unroll
    for (int g = 0; g < NREP; ++g) {
        cA += hrep[0][g * HSTRIDE + tid];
        cB += hrep[1][g * HSTRIDE + tid];
    }

    int sA = cA, sB = cB;
    #pragma unroll
    for (int off = 1; off < 64; off <<= 1) {
        int tA = __shfl_down(sA, off);
        int tB = __shfl_down(sB, off);
        if (lane + off < 64) { sA += tA; sB += tB; }
    }
    if (lane == 0) { wtot[0][wave] = sA; wtot[1][wave] = sB; }
    __syncthreads();
    #pragma unroll
    for (int w = 0; w < 4; ++w)
        if (w > wave) { sA += wtot[0][w]; sB += wtot[1][w]; }

    if (sA >= KSEL && sA - cA < KSEL) { s_dig[0] = (unsigned)tid; s_krem[0] = KSEL - (sA - cA); }
    if (sB >= KSEL && sB - cB < KSEL) { s_dig[1] = (unsigned)tid; s_krem[1] = KSEL - (sB - cB); }
    __syncthreads();
    unsigned prefA = s_dig[0] << 24, prefB = s_dig[1] << 24;
    int      kremA = s_krem[0],      kremB = s_krem[1];

    // ---- passes 1-3: few matching elements -> single histograms ----
    #pragma unroll 1
    for (int pass = 1; pass < 4; ++pass) {
        const int shift = 24 - pass * 8;
        const unsigned himask = 0xFFFFFFFFu << (shift + 8);

        #pragma unroll
        for (int r = 0; r < VPT; ++r) {
            unsigned bA = hbA[r] & 0x7FFFFFFFu;
            unsigned bB = hbB[r] & 0x7FFFFFFFu;
            if ((bA & himask) == prefA) atomicAdd(&hist1[0][(bA >> shift) & 255u], 1);
            if ((bB & himask) == prefB) atomicAdd(&hist1[1][(bB >> shift) & 255u], 1);
        }
        __syncthreads();

        cA = hist1[0][tid]; cB = hist1[1][tid];
        sA = cA; sB = cB;
        #pragma unroll
        for (int off = 1; off < 64; off <<= 1) {
            int tA = __shfl_down(sA, off);
            int tB = __shfl_down(sB, off);
            if (lane + off < 64) { sA += tA; sB += tB; }
        }
        if (lane == 0) { wtot[0][wave] = sA; wtot[1][wave] = sB; }
        __syncthreads();
        #pragma unroll
        for (int w = 0; w < 4; ++w)
            if (w > wave) { sA += wtot[0][w]; sB += wtot[1][w]; }

        if (sA >= kremA && sA - cA < kremA) { s_dig[0] = (unsigned)tid; s_krem[0] = kremA - (sA - cA); }
        if (sB >= kremB && sB - cB < kremB) { s_dig[1] = (unsigned)tid; s_krem[1] = kremB - (sB - cB); }
        hist1[0][tid] = 0;   // re-zero for next pass (same-thread, ordered)
        hist1[1][tid] = 0;
        __syncthreads();
        prefA |= s_dig[0] << shift;  kremA = s_krem[0];
        prefB |= s_dig[1] << shift;  kremB = s_krem[1];
    }

    // ---- keep iff |h| >= thr (bit compare; tie sets coincide with ref) ----
    #pragma unroll
    for (int j = 0; j < 4; ++j) {
        float4 oA, oB;
        float* pa = &oA.x;
        float* pb = &oB.x;
        #pragma unroll
        for (int c4 = 0; c4 < 4; ++c4) {
            unsigned ha = hbA[j*4+c4], hb = hbB[j*4+c4];
            pa[c4] = ((ha & 0x7FFFFFFFu) >= prefA) ? __uint_as_float(ha) : 0.0f;
            pb[c4] = ((hb & 0x7FFFFFFFu) >= prefB) ? __uint_as_float(hb) : 0.0f;
        }
        oa[j * NTHREADS + tid] = oA;
        ob[j * NTHREADS + tid] = oB;
    }
}

extern "C" void kernel_launch(void* const* d_in, const int* in_sizes, int n_in,
                              void* d_out, int out_size, void* d_ws, size_t ws_size,
                              hipStream_t stream) {
    const float* x   = (const float*)d_in[0];
    float*       out = (float*)d_out;
    const int rows = in_sizes[0] / DIM;   // 4 * 4096 = 16384
    topk_silu_kernel<<<rows / 2, NTHREADS, 0, stream>>>(x, out);
}

// Round 8
// 115.813 us; speedup vs baseline: 1.0251x; 1.0251x over previous
//
#include <hip/hip_runtime.h>
#include <math.h>

#define DIM      4096
#define KSEL     2048
#define NTHREADS 256
#define VPT      16            // DIM / NTHREADS
#define LO_BITS  0x3D800000u   // 0.0625  — threshold search window lo
#define HI_BITS  0x3F800000u   // 1.0     — threshold search window hi
#define BSHIFT   17            // (HI-LO)>>17 == 256 buckets
#define CAP      256           // candidate list capacity

// ---- bit-exact XLA-CPU silu: s = 1/(1+cephes_exp_fma(-x)); h = x*s ----
// Verified absmax == 0.0 in round 4. DO NOT MODIFY.
__device__ __forceinline__ float cephes_expf_fma(float x) {
    const float LOG2EF = 1.44269504088896341f;
    const float C1     = 0.693359375f;
    const float C2     = -2.12194440e-4f;
    float z0 = __builtin_fmaf(x, LOG2EF, 0.5f);
    float fx = floorf(z0);
    float r  = __fsub_rn(x, __fmul_rn(fx, C1));
    r = __builtin_fmaf(fx, -C2, r);
    float zz = __fmul_rn(r, r);
    float y  = 1.9875691500e-4f;
    y = __builtin_fmaf(y, r, 1.3981999507e-3f);
    y = __builtin_fmaf(y, r, 8.3334519073e-3f);
    y = __builtin_fmaf(y, r, 4.1665795894e-2f);
    y = __builtin_fmaf(y, r, 1.6666665459e-1f);
    y = __builtin_fmaf(y, r, 5.0000001201e-1f);
    y = __builtin_fmaf(y, zz, r);
    y = __fadd_rn(y, 1.0f);
    int n = (int)fx;
    float scale = __int_as_float((n + 127) << 23);
    return __fmul_rn(y, scale);
}

__device__ __forceinline__ float silu_ref(float x) {
    float e = cephes_expf_fma(-x);
    float s = __fdiv_rn(1.0f, __fadd_rn(1.0f, e));
    return __fmul_rn(x, s);
}

__global__ __launch_bounds__(NTHREADS) void topk_silu_kernel(
    const float* __restrict__ x, float* __restrict__ out)
{
    const int tid  = threadIdx.x;
    const int lane = tid & 63;
    const int wave = tid >> 6;

    const float4* __restrict__ xr4 =
        reinterpret_cast<const float4*>(x + (size_t)blockIdx.x * DIM);
    float4* __restrict__ or4 =
        reinterpret_cast<float4*>(out + (size_t)blockIdx.x * DIM);

    __shared__ int      hist[256];
    __shared__ int      wred[4];     // wave partials: n_hi reduce
    __shared__ int      wscan[4];    // wave partials: suffix scan
    __shared__ unsigned s_dig;
    __shared__ int      s_krem;
    __shared__ int      s_nb;
    __shared__ int      s_found;
    __shared__ unsigned s_thr;
    __shared__ int      s_cnt;
    __shared__ unsigned list[CAP];

    // ---- load + bit-exact f32 silu; hb = h bit patterns ----
    unsigned hb[VPT];
    #pragma unroll
    for (int j = 0; j < 4; ++j) {
        float4 v = xr4[j * NTHREADS + tid];
        const float* vp = &v.x;
        #pragma unroll
        for (int c4 = 0; c4 < 4; ++c4)
            hb[j*4+c4] = __float_as_uint(silu_ref(vp[c4]));
    }

    hist[tid] = 0;
    if (tid == 0) { s_found = 0; s_cnt = 0; s_thr = 0xFFFFFFFFu; }
    __syncthreads();

    // ---- single bucket pass over the threshold window + above-count ----
    int nhi = 0;
    #pragma unroll
    for (int r = 0; r < VPT; ++r) {
        unsigned k  = hb[r] & 0x7FFFFFFFu;
        nhi += (k >= HI_BITS) ? 1 : 0;
        unsigned bk = (k - LO_BITS) >> BSHIFT;   // wraps huge if k < LO
        if (bk < 256u) atomicAdd(&hist[bk], 1);
    }
    #pragma unroll
    for (int off = 32; off; off >>= 1) nhi += __shfl_xor(nhi, off);
    if (lane == 0) wred[wave] = nhi;
    __syncthreads();
    const int n_hi = wred[0] + wred[1] + wred[2] + wred[3];

    // suffix scan over 256 buckets (count of keys >= bucket start, + n_hi)
    int c = hist[tid];
    int s = c;
    #pragma unroll
    for (int off = 1; off < 64; off <<= 1) {
        int t = __shfl_down(s, off);
        if (lane + off < 64) s += t;
    }
    if (lane == 0) wscan[wave] = s;
    __syncthreads();
    #pragma unroll
    for (int w = 0; w < 4; ++w)
        if (w > wave) s += wscan[w];
    s += n_hi;

    if (s >= KSEL && s - c < KSEL) {   // K-th largest lands in this bucket
        s_dig   = (unsigned)tid;
        s_krem  = KSEL - (s - c);
        s_nb    = c;
        s_found = 1;
    }
    __syncthreads();

    unsigned thr_bits;
    if (s_found && s_nb <= CAP) {
        // ---- fast path: exact rank among the few bucket candidates ----
        const unsigned bsel = s_dig;
        const int      krem = s_krem;
        const int      nb   = s_nb;
        #pragma unroll
        for (int r = 0; r < VPT; ++r) {
            unsigned k = hb[r] & 0x7FFFFFFFu;
            if (((k - LO_BITS) >> BSHIFT) == bsel) {
                int idx = atomicAdd(&s_cnt, 1);
                list[idx] = k;
            }
        }
        __syncthreads();
        if (tid < nb) {
            unsigned ki = list[tid];
            int rk = 0;
            for (int j = 0; j < nb; ++j) rk += (list[j] > ki) ? 1 : 0;
            if (rk < krem) atomicMin(&s_thr, ki);
        }
        __syncthreads();
        thr_bits = s_thr;
    } else {
        // ---- fallback: full 4-pass radix select (distribution-free) ----
        unsigned prefix = 0;
        int      krem   = KSEL;
        #pragma unroll 1
        for (int pass = 0; pass < 4; ++pass) {
            const int shift = 24 - pass * 8;
            hist[tid] = 0;
            __syncthreads();
            const unsigned himask =
                (pass == 0) ? 0u : (0xFFFFFFFFu << (shift + 8));
            #pragma unroll
            for (int r = 0; r < VPT; ++r) {
                unsigned k = hb[r] & 0x7FFFFFFFu;
                if ((k & himask) == prefix)
                    atomicAdd(&hist[(k >> shift) & 255u], 1);
            }
            __syncthreads();
            c = hist[tid];
            s = c;
            #pragma unroll
            for (int off = 1; off < 64; off <<= 1) {
                int t = __shfl_down(s, off);
                if (lane + off < 64) s += t;
            }
            if (lane == 0) wscan[wave] = s;
            __syncthreads();
            #pragma unroll
            for (int w = 0; w < 4; ++w)
                if (w > wave) s += wscan[w];
            if (s >= krem && s - c < krem) {
                s_dig  = (unsigned)tid;
                s_krem = krem - (s - c);
            }
            __syncthreads();
            prefix |= s_dig << shift;
            krem    = s_krem;
        }
        thr_bits = prefix;
    }

    // ---- keep iff |h| >= thr (bit compare; tie sets coincide with ref) ----
    #pragma unroll
    for (int j = 0; j < 4; ++j) {
        float4 o;
        float* op = &o.x;
        #pragma unroll
        for (int c4 = 0; c4 < 4; ++c4) {
            unsigned h = hb[j*4+c4];
            op[c4] = ((h & 0x7FFFFFFFu) >= thr_bits) ? __uint_as_float(h) : 0.0f;
        }
        or4[j * NTHREADS + tid] = o;
    }
}

extern "C" void kernel_launch(void* const* d_in, const int* in_sizes, int n_in,
                              void* d_out, int out_size, void* d_ws, size_t ws_size,
                              hipStream_t stream) {
    const float* x   = (const float*)d_in[0];
    float*       out = (float*)d_out;
    const int rows = in_sizes[0] / DIM;   // 4 * 4096 = 16384
    topk_silu_kernel<<<rows, NTHREADS, 0, stream>>>(x, out);
}